// Round 9
// baseline (44.822 us; speedup 1.0000x reference)
//
#include <hip/hip_runtime.h>
#include <hip/hip_fp16.h>

// y[b,q] = sum_{d,f} amp[b,d,f] * sin(x_q[b,q,d] * freq[b,d,f])
//
// R9: SINGLE dispatch (floor-hypothesis test: totals look like ~20us fixed
// replay overhead + device time; minimize dispatch count to 1).
// Block = (b, 256-q slice), 512 thr, 66 KB LDS -> 2 blocks/CU, 4 waves/SIMD.
//   phase A: build 32 tables (d-half 0) of g(x)=sum_f amp*sin(freq*x),
//            512 pts over [-8,8], Chebyshev recurrence s_{k+1}=w*s_k-s_{k-1},
//            entries packed half2(value, slope)  [R5-R8 validated, absmax 0.5]
//   phase B: lookup pass over d 0..31, per-q partials in regs (shfl reduce)
//   phase C: rebuild tables for d-half 1
//   phase D: lookup pass d 32..63, add partials, plain coalesced store.
// x-loads lane-contiguous: lane l -> q-sub l>>4, d-pair (l&15)*2 (R7 fix).
#define ND 64
#define NF 16
#define TPTS 512
#define TROW 516       // padded row stride (uints): decorrelates banks
#define SEGP 16
#define DELTA 0.03125f
#define XSCALE 32.0f
#define XBIAS 256.0f   // (x+8)*32
#define IMAX 510.99f   // i+1 <= 511
#define QSL 256        // q's per block

__global__ __launch_bounds__(512, 4) void sinreg_fused(
    const float* __restrict__ z,
    const float* __restrict__ xq,
    float* __restrict__ out,
    int B, int Q) {
  __shared__ unsigned s_tbl[32 * TROW];  // 66 KB: one 32-d half-table

  const int b   = blockIdx.y;
  const int qsl = blockIdx.x;
  const int tid = threadIdx.x;
  const int lane = tid & 63;
  const int wv   = tid >> 6;          // 0..7
  const int qsub = lane >> 4;         // 0..3
  const int dp   = (lane & 15) * 2;   // local d pair within the staged half

  const int q0 = qsl * QSL + wv * 32; // this wave's 32 q's (8 iters x 4)
  const float* __restrict__ zb = z + (size_t)b * (2 * ND * NF);
  constexpr float INV2PI = 0.15915494309189535f;

  const unsigned* __restrict__ trow0 = &s_tbl[dp * TROW];
  const unsigned* __restrict__ trow1 = trow0 + TROW;

  float acc[8];

  // Build 32 tables for d-half H. (d,seg) pairs: dl=tid&31 (lane-varying ->
  // LDS write banks spread, R5 layout), sg covers 0..31 over pp=0,1.
#define BUILD(H)                                                               \
  _Pragma("unroll")                                                            \
  for (int pp = 0; pp < 2; ++pp) {                                             \
    const int dl = tid & 31;                                                   \
    const int sg = (tid >> 5) + 16 * pp;                                       \
    const int k0 = sg * SEGP;                                                  \
    const float xs = -8.0f + k0 * DELTA;                                       \
    const float4* __restrict__ ap4 =                                           \
        reinterpret_cast<const float4*>(zb + ((H) * 32 + dl) * NF);            \
    const float4* __restrict__ fp4 =                                           \
        reinterpret_cast<const float4*>(zb + ND * NF + ((H) * 32 + dl) * NF);  \
    float g[SEGP + 1];                                                         \
    _Pragma("unroll") for (int k = 0; k <= SEGP; ++k) g[k] = 0.f;              \
    _Pragma("unroll") for (int f4 = 0; f4 < 4; ++f4) {                         \
      const float4 fv4 = fp4[f4];                                              \
      const float4 av4 = ap4[f4];                                              \
      const float fvs[4] = {fv4.x, fv4.y, fv4.z, fv4.w};                       \
      const float avs[4] = {av4.x, av4.y, av4.z, av4.w};                       \
      _Pragma("unroll") for (int fj = 0; fj < 4; ++fj) {                       \
        const float fv = fvs[fj], av = avs[fj];                                \
        float s0 = __builtin_amdgcn_sinf(                                      \
            __builtin_amdgcn_fractf(fv * xs * INV2PI));                        \
        float s1 = __builtin_amdgcn_sinf(                                      \
            __builtin_amdgcn_fractf(fv * (xs + DELTA) * INV2PI));              \
        const float th2 = (fv * DELTA) * (fv * DELTA);                         \
        const float w = fmaf(th2, fmaf(th2, 0.0833333333f, -1.0f), 2.0f);      \
        g[0] = fmaf(av, s0, g[0]);                                             \
        g[1] = fmaf(av, s1, g[1]);                                             \
        _Pragma("unroll") for (int k = 2; k <= SEGP; ++k) {                    \
          const float s2 = fmaf(w, s1, -s0);                                   \
          g[k] = fmaf(av, s2, g[k]);                                           \
          s0 = s1; s1 = s2;                                                    \
        }                                                                      \
      }                                                                        \
    }                                                                          \
    unsigned pk[SEGP];                                                         \
    _Pragma("unroll") for (int k = 0; k < SEGP; ++k) {                         \
      __half2 h;                                                               \
      h.x = __float2half(g[k]);                                                \
      h.y = __float2half(g[k + 1] - g[k]);                                     \
      pk[k] = *reinterpret_cast<unsigned*>(&h);                                \
    }                                                                          \
    uint4* __restrict__ dst =                                                  \
        reinterpret_cast<uint4*>(&s_tbl[dl * TROW + k0]);                      \
    _Pragma("unroll") for (int j = 0; j < 4; ++j)                              \
      dst[j] = make_uint4(pk[4 * j], pk[4 * j + 1], pk[4 * j + 2],             \
                          pk[4 * j + 3]);                                      \
  }

#define LOOKUP2(R, XPTR)                                                       \
  {                                                                            \
    const float2 x2 = *reinterpret_cast<const float2*>(XPTR);                  \
    float tt = fmaf(x2.x, XSCALE, XBIAS);                                      \
    tt = fminf(fmaxf(tt, 0.0f), IMAX);                                         \
    unsigned i = (unsigned)tt;                                                 \
    float u = tt - (float)i;                                                   \
    unsigned pv = trow0[i];                                                    \
    float2 gs = __half22float2(*reinterpret_cast<const __half2*>(&pv));        \
    R = fmaf(gs.y, u, gs.x);                                                   \
    tt = fmaf(x2.y, XSCALE, XBIAS);                                            \
    tt = fminf(fmaxf(tt, 0.0f), IMAX);                                         \
    i = (unsigned)tt;                                                          \
    u = tt - (float)i;                                                         \
    pv = trow1[i];                                                             \
    gs = __half22float2(*reinterpret_cast<const __half2*>(&pv));               \
    R = fmaf(gs.y, u, gs.x + R);                                               \
    R += __shfl_xor(R, 1);                                                     \
    R += __shfl_xor(R, 2);                                                     \
    R += __shfl_xor(R, 4);                                                     \
    R += __shfl_xor(R, 8);                                                     \
  }

  // ---- phase A: build half 0 (d 0..31) ----
  BUILD(0);
  __syncthreads();

  // ---- phase B: lookup pass 0 ----
  {
    const float* __restrict__ xp =
        xq + ((size_t)b * Q + q0 + qsub) * ND + dp;  // half-0 columns
    #pragma unroll
    for (int it = 0; it < 8; ++it) {
      float r;
      LOOKUP2(r, xp + (size_t)it * 4 * ND);
      acc[it] = r;
    }
  }
  __syncthreads();  // all table reads done before rebuild

  // ---- phase C: build half 1 (d 32..63) ----
  BUILD(1);
  __syncthreads();

  // ---- phase D: lookup pass 1 + store ----
  {
    const float* __restrict__ xp =
        xq + ((size_t)b * Q + q0 + qsub) * ND + 32 + dp;  // half-1 columns
    #pragma unroll
    for (int it = 0; it < 8; ++it) {
      float r;
      LOOKUP2(r, xp + (size_t)it * 4 * ND);
      if ((lane & 15) == 0)
        out[(size_t)b * Q + q0 + it * 4 + qsub] = acc[it] + r;
    }
  }
#undef BUILD
#undef LOOKUP2
}

extern "C" void kernel_launch(void* const* d_in, const int* in_sizes, int n_in,
                              void* d_out, int out_size, void* d_ws, size_t ws_size,
                              hipStream_t stream) {
  const float* z  = (const float*)d_in[0];
  const float* xq = (const float*)d_in[1];
  float* out = (float*)d_out;

  const int B = in_sizes[0] / (2 * ND * NF);  // 32
  const int Q = in_sizes[1] / (B * ND);       // 4096

  // one dispatch: (Q/QSL) x B = 16 x 32 = 512 blocks, 512 thr, 66 KB LDS
  dim3 grid(Q / QSL, B);
  sinreg_fused<<<grid, 512, 0, stream>>>(z, xq, out, B, Q);
}

// Round 10
// 22.910 us; speedup vs baseline: 1.9564x; 1.9564x over previous
//
#include <hip/hip_runtime.h>
#include <hip/hip_fp16.h>

// y[b,q] = sum_{d,f} amp[b,d,f] * sin(x_q[b,q,d] * freq[b,d,f])
//
// R10: best-known structure (R8 two-dispatch, no atomics/memset) + trims.
//  K1 (build): per (b,d) 512-pt table of g(x)=sum_f amp*sin(freq*x) over
//     [-8,8], Chebyshev recurrence, entries packed half2(value, slope).
//     [R5-R9 validated numerics, absmax 0.5]
//  K2 (lookup): block = (b, 256-q slice), 512 thr, 66 KB LDS (padded rows).
//     Pass 0: stage d0..31 table, load BOTH d-halves of x as float4
//     (half-1 parked in regs), 4 lookups + 3-shfl reduce; pass 1: restage
//     d32..63, zero global loads, add partials, coalesced store.
//     Lane l: q-sub = l>>3, d-quad = (l&7)*4 -> 8 lanes cover a 128B row half.
#define ND 64
#define NF 16
#define TPTS 512
#define TROW 516       // padded LDS row stride (uints)
#define SEGP 16
#define DELTA 0.03125f
#define XSCALE 32.0f
#define XBIAS 256.0f   // (x+8)*32
#define IMAX 510.99f   // i+1 <= 511
#define QSL 256        // q's per lookup block

// ---------------- K1: build packed (value,slope) tables ----------------
__global__ __launch_bounds__(256) void sinreg_build(
    const float* __restrict__ z, unsigned* __restrict__ tblg, int B) {
  const int t = blockIdx.x * 256 + threadIdx.x;   // (b, d, seg)
  const int b   = t >> 11;
  const int d   = (t >> 5) & (ND - 1);
  const int seg = t & 31;
  const int k0  = seg * SEGP;
  const float xs = -8.0f + k0 * DELTA;

  const float* __restrict__ zb = z + (size_t)b * (2 * ND * NF);
  const float* __restrict__ ap = zb + d * NF;            // amp[d][f]
  const float* __restrict__ fp = zb + ND * NF + d * NF;  // freq[d][f]
  constexpr float INV2PI = 0.15915494309189535f;

  float g[SEGP + 1];  // one extra point for the last slope
  #pragma unroll
  for (int k = 0; k <= SEGP; ++k) g[k] = 0.f;

  #pragma unroll
  for (int f = 0; f < NF; ++f) {
    const float fv = fp[f], av = ap[f];
    float s0 = __builtin_amdgcn_sinf(__builtin_amdgcn_fractf(fv * xs * INV2PI));
    float s1 = __builtin_amdgcn_sinf(
        __builtin_amdgcn_fractf(fv * (xs + DELTA) * INV2PI));
    const float th2 = (fv * DELTA) * (fv * DELTA);
    const float w = fmaf(th2, fmaf(th2, 0.0833333333f, -1.0f), 2.0f);  // 2cos
    g[0] = fmaf(av, s0, g[0]);
    g[1] = fmaf(av, s1, g[1]);
    #pragma unroll
    for (int k = 2; k <= SEGP; ++k) {
      const float s2 = fmaf(w, s1, -s0);  // s_{k+1} = w*s_k - s_{k-1}
      g[k] = fmaf(av, s2, g[k]);
      s0 = s1; s1 = s2;
    }
  }

  unsigned pk[SEGP];
  #pragma unroll
  for (int k = 0; k < SEGP; ++k) {
    __half2 h;
    h.x = __float2half(g[k]);
    h.y = __float2half(g[k + 1] - g[k]);
    pk[k] = *reinterpret_cast<unsigned*>(&h);
  }
  uint4* __restrict__ dst =
      reinterpret_cast<uint4*>(tblg + ((size_t)(b * ND + d) * TPTS) + k0);
  #pragma unroll
  for (int j = 0; j < 4; ++j)
    dst[j] = make_uint4(pk[4 * j], pk[4 * j + 1], pk[4 * j + 2], pk[4 * j + 3]);
}

// ---------------- K2: two-pass lookup ----------------
__global__ __launch_bounds__(512, 4) void sinreg_lookup(
    const unsigned* __restrict__ tblg,
    const float* __restrict__ xq,
    float* __restrict__ out,
    int B, int Q) {
  __shared__ unsigned s_tbl[32 * TROW];  // 66 KB, padded rows

  const int b   = blockIdx.y;
  const int qsl = blockIdx.x;
  const int tid = threadIdx.x;
  const int lane = tid & 63;
  const int wv   = tid >> 6;          // 0..7
  const int qsub = lane >> 3;         // 0..7 : q within the wave's 8-row group
  const int dq   = (lane & 7) * 4;    // local d quad within the staged half

  const int q0 = qsl * QSL + wv * 32; // this wave's 32 q's (4 iters x 8)

  const unsigned* __restrict__ tr0 = &s_tbl[(dq + 0) * TROW];
  const unsigned* __restrict__ tr1 = &s_tbl[(dq + 1) * TROW];
  const unsigned* __restrict__ tr2 = &s_tbl[(dq + 2) * TROW];
  const unsigned* __restrict__ tr3 = &s_tbl[(dq + 3) * TROW];

  // stage one 32-d half-table (packed rows of 512 -> padded rows of 516)
#define STAGE(H)                                                               \
  {                                                                            \
    const uint4* __restrict__ src = reinterpret_cast<const uint4*>(            \
        tblg + (size_t)(b * ND + (H) * 32) * TPTS);                            \
    _Pragma("unroll")                                                          \
    for (int i = 0; i < 8; ++i) {                                              \
      const int idx = tid + i * 512;          /* 0..4095 */                    \
      const int row = idx >> 7;               /* 0..31  */                     \
      const int col = (idx & 127) * 4;        /* 0..508 */                     \
      *reinterpret_cast<uint4*>(&s_tbl[row * TROW + col]) = src[idx];          \
    }                                                                          \
  }

#define LK(TR, XV, R)                                                          \
  {                                                                            \
    float tt = fmaf((XV), XSCALE, XBIAS);                                      \
    tt = fminf(fmaxf(tt, 0.0f), IMAX);                                         \
    const unsigned i = (unsigned)tt;                                           \
    const float u = tt - (float)i;                                             \
    const unsigned pv = (TR)[i];                                               \
    const float2 gs = __half22float2(*reinterpret_cast<const __half2*>(&pv));  \
    R += fmaf(gs.y, u, gs.x);                                                  \
  }

  float accq[4];
  float4 xh1[4];  // half-1 x values parked in registers

  // ---- pass 0: d 0..31 (and prefetch half-1 x) ----
  STAGE(0);
  __syncthreads();
  #pragma unroll
  for (int it = 0; it < 4; ++it) {
    const float* __restrict__ xrow =
        xq + ((size_t)b * Q + q0 + it * 8 + qsub) * ND + dq;
    const float4 xa = *reinterpret_cast<const float4*>(xrow);
    xh1[it] = *reinterpret_cast<const float4*>(xrow + 32);
    float r = 0.f;
    LK(tr0, xa.x, r) LK(tr1, xa.y, r) LK(tr2, xa.z, r) LK(tr3, xa.w, r)
    r += __shfl_xor(r, 1);
    r += __shfl_xor(r, 2);
    r += __shfl_xor(r, 4);
    accq[it] = r;
  }
  __syncthreads();  // all pass-0 table reads done before restage

  // ---- pass 1: d 32..63 (zero global loads) ----
  STAGE(1);
  __syncthreads();
  #pragma unroll
  for (int it = 0; it < 4; ++it) {
    const float4 xa = xh1[it];
    float r = 0.f;
    LK(tr0, xa.x, r) LK(tr1, xa.y, r) LK(tr2, xa.z, r) LK(tr3, xa.w, r)
    r += __shfl_xor(r, 1);
    r += __shfl_xor(r, 2);
    r += __shfl_xor(r, 4);
    if ((lane & 7) == 0)
      out[(size_t)b * Q + q0 + it * 8 + qsub] = accq[it] + r;
  }
#undef STAGE
#undef LK
}

// ---------------- fallback (direct v_sin, R3-validated) ----------------
__global__ __launch_bounds__(256, 4) void sinreg_direct(
    const float* __restrict__ z, const float* __restrict__ xq,
    float* __restrict__ out, int B, int Q) {
  __shared__ float s_part[4][64];
  const int b = blockIdx.y;
  const int lane = threadIdx.x & 63;
  const int wv = __builtin_amdgcn_readfirstlane((int)(threadIdx.x >> 6));
  const int q = blockIdx.x * 64 + lane;
  const float* __restrict__ zb  = z + (size_t)b * (2 * ND * NF);
  const float* __restrict__ amp = zb + (16 * wv) * NF;
  const float* __restrict__ frq = zb + ND * NF + (16 * wv) * NF;
  const float4* __restrict__ xrow =
      reinterpret_cast<const float4*>(xq + ((size_t)b * Q + q) * ND + 16 * wv);
  float4 xv0 = xrow[0], xv1 = xrow[1], xv2 = xrow[2], xv3 = xrow[3];
  constexpr float INV2PI = 0.15915494309189535f;
  const float xs[16] = {
      xv0.x * INV2PI, xv0.y * INV2PI, xv0.z * INV2PI, xv0.w * INV2PI,
      xv1.x * INV2PI, xv1.y * INV2PI, xv1.z * INV2PI, xv1.w * INV2PI,
      xv2.x * INV2PI, xv2.y * INV2PI, xv2.z * INV2PI, xv2.w * INV2PI,
      xv3.x * INV2PI, xv3.y * INV2PI, xv3.z * INV2PI, xv3.w * INV2PI};
  float acc0 = 0.f, acc1 = 0.f, acc2 = 0.f, acc3 = 0.f;
  #pragma unroll
  for (int dd = 0; dd < 16; ++dd) {
    const float xsd = xs[dd];
    #pragma unroll
    for (int f = 0; f < NF; f += 4) {
      acc0 = fmaf(__builtin_amdgcn_sinf(__builtin_amdgcn_fractf(xsd * frq[dd * NF + f + 0])), amp[dd * NF + f + 0], acc0);
      acc1 = fmaf(__builtin_amdgcn_sinf(__builtin_amdgcn_fractf(xsd * frq[dd * NF + f + 1])), amp[dd * NF + f + 1], acc1);
      acc2 = fmaf(__builtin_amdgcn_sinf(__builtin_amdgcn_fractf(xsd * frq[dd * NF + f + 2])), amp[dd * NF + f + 2], acc2);
      acc3 = fmaf(__builtin_amdgcn_sinf(__builtin_amdgcn_fractf(xsd * frq[dd * NF + f + 3])), amp[dd * NF + f + 3], acc3);
    }
  }
  s_part[wv][lane] = (acc0 + acc1) + (acc2 + acc3);
  __syncthreads();
  if (threadIdx.x < 64) {
    float r = (s_part[0][lane] + s_part[1][lane]) + (s_part[2][lane] + s_part[3][lane]);
    out[(size_t)b * Q + (size_t)blockIdx.x * 64 + lane] = r;
  }
}

extern "C" void kernel_launch(void* const* d_in, const int* in_sizes, int n_in,
                              void* d_out, int out_size, void* d_ws, size_t ws_size,
                              hipStream_t stream) {
  const float* z  = (const float*)d_in[0];
  const float* xq = (const float*)d_in[1];
  float* out = (float*)d_out;

  const int B = in_sizes[0] / (2 * ND * NF);  // 32
  const int Q = in_sizes[1] / (B * ND);       // 4096

  const size_t tbl_bytes = (size_t)B * ND * TPTS * sizeof(unsigned);  // 4 MB
  if (ws_size < tbl_bytes) {  // fallback: direct evaluation (R3, validated)
    dim3 grid(Q / 64, B);
    sinreg_direct<<<grid, 256, 0, stream>>>(z, xq, out, B, Q);
    return;
  }

  unsigned* tblg = (unsigned*)d_ws;

  // K1: build all (b,d) tables once. threads = B*ND*32 = 65536
  sinreg_build<<<dim3((B * ND * 32) / 256), 256, 0, stream>>>(z, tblg, B);

  // K2: (Q/QSL) x B = 512 blocks, 512 thr, 66 KB LDS, no atomics/memset
  dim3 grid(Q / QSL, B);
  sinreg_lookup<<<grid, 512, 0, stream>>>(tblg, xq, out, B, Q);
}